// Round 5
// baseline (222.699 us; speedup 1.0000x reference)
//
#include <hip/hip_runtime.h>

typedef _Float16 half_t;
typedef __attribute__((ext_vector_type(2))) _Float16 halfx2;
typedef __attribute__((ext_vector_type(8))) _Float16 halfx8;
typedef __attribute__((ext_vector_type(4))) float floatx4;

#define N_NODES 200000
#define N_EDGES 800000
#define NPOS    16384     // 128*128 feature-map positions
#define KIN     484       // 480 backbone + 4 seg channels

// histogram geometry: 32 edge slices x 8 node ranges, 8-bit packed counters
#define NSLICE  32
#define NRANGE  8
#define RNODES  25000     // nodes per range
#define RWORDS  6250      // packed u32 words per range (4 nodes/word)
#define CWORDS  50000     // packed words per copy (N_NODES/4)
#define SCHUNK  12500     // int4 chunks per edge slice (400,000/32)

// kT grid layout
#define KT_TRANS 4096     // 256 pos-tiles x 16 k-tiles (64 pos x 32 k each)
#define KT_HISTO (KT_TRANS + NSLICE * NRANGE)   // 4096..4351
#define KT_W1F   (KT_HISTO + 8)                 // 4352..4359
#define KT_GRID  (KT_W1F + 1)                   // 4360 = w2f + maxd-zero

// ws layout (bytes)
#define WS_DEGPK 0           // 32 copies * 200,000 B = 6,400,000
#define WS_DEG   6400000     // 200,000 * u32 = 800,000 (final degrees)
#define WS_MAXD  7200000     // 64
#define WS_W2F   7200064     // 128*128 fp16 fragment-ordered = 32768
#define WS_W1F   7232832     // 128*512 fp16 fragment-ordered = 131072
#define WS_U     7363904     // 16384*128 fp16 = 4 MiB
#define WS_BT    11558208    // 16384*512 fp16 = 16 MiB (end ~28.3 MB)

// ---------------------------------------------------------------- kT
// bid < 4096:       B-transpose: Bt[pos][k512] fp16, zero-padded k>=484.
//                   Wave w covers k-octet kb+w*8: 8 coalesced 256B row
//                   loads, 1 halfx8 store/lane. No LDS.
// 4096 <= bid<4352: degree histogram (verbatim round-3 body).
// 4352 <= bid<4360: W1 -> fragment-ordered w1f:
//                   w1f[(t*16+kbi)*512 + lane*8 + i] =
//                     W1[t*16+(lane&15)][2 + kbi*32 + (lane>>4)*8 + i]
// bid == 4360:      W2 -> fragment-ordered w2f (round-4 layout); tid 0
//                   zeroes maxd (replaces the hipMemsetAsync enqueue).
__global__ __launch_bounds__(256) void kT(const float* __restrict__ bb,
                                          const float* __restrict__ seg,
                                          const int* __restrict__ e,
                                          const float* __restrict__ W1,
                                          const float* __restrict__ W2,
                                          unsigned* __restrict__ degpk,
                                          half_t* __restrict__ Bt,
                                          half_t* __restrict__ w1f,
                                          half_t* __restrict__ w2f,
                                          unsigned* __restrict__ maxd) {
  __shared__ __align__(16) char sm[25600];   // histogram blocks only

  const int tid = threadIdx.x;
  const int bid = blockIdx.x;
  const int wave = tid >> 6, lane = tid & 63;
  const int l15 = lane & 15, q4 = lane >> 4;

  if (bid < KT_TRANS) {
    // -------- B transpose --------
    const int pt = bid >> 4, kt = bid & 15;
    const int p0 = pt * 64, kb = kt * 32;
    const int kw = kb + wave * 8;
    halfx8 h;
    for (int i = 0; i < 8; ++i) {
      int k = kw + i;
      float v = 0.f;
      if (k < 480)      v = bb[(long)k * NPOS + p0 + lane];
      else if (k < KIN) v = seg[(long)(k - 480) * NPOS + p0 + lane];
      h[i] = (half_t)v;
    }
    *(halfx8*)&Bt[(long)(p0 + lane) * 512 + kw] = h;
  } else if (bid < KT_HISTO) {
    // -------- degree histogram block (verbatim) --------
    unsigned* cnt = (unsigned*)sm;         // [0,64) dump slots, [64,6314) counters
    const int hb = bid - KT_TRANS;         // 0..255
    const int s  = hb >> 3;                // edge slice 0..31
    const int r  = hb & 7;                 // node range 0..7
    const int lo = r * RNODES;

    for (int i = tid; i < 64 + RWORDS; i += 256) cnt[i] = 0;
    __syncthreads();

#define HBIN(v) { unsigned d = (unsigned)(v) - (unsigned)lo;                 \
                  bool ok = d < (unsigned)RNODES;                            \
                  unsigned w = ok ? (d >> 2) + 64u : (unsigned)lane;         \
                  unsigned a_ = ok ? (1u << ((d & 3u) << 3)) : 0u;           \
                  atomicAdd(&cnt[w], a_); }

    const int4* E4 = (const int4*)e + s * SCHUNK;
    for (int base = 0; base < 12288; base += 1024) {   // 12 iters, 4-deep ILP
      int4 a = E4[base + tid];
      int4 b = E4[base + tid + 256];
      int4 c = E4[base + tid + 512];
      int4 d4 = E4[base + tid + 768];
      HBIN(a.x); HBIN(a.y); HBIN(a.z); HBIN(a.w);
      HBIN(b.x); HBIN(b.y); HBIN(b.z); HBIN(b.w);
      HBIN(c.x); HBIN(c.y); HBIN(c.z); HBIN(c.w);
      HBIN(d4.x); HBIN(d4.y); HBIN(d4.z); HBIN(d4.w);
    }
    if (tid < SCHUNK - 12288) {            // tail: 212 int4
      int4 a = E4[12288 + tid];
      HBIN(a.x); HBIN(a.y); HBIN(a.z); HBIN(a.w);
    }
#undef HBIN
    __syncthreads();

    unsigned* dst = degpk + s * CWORDS + r * RWORDS;
    for (int i = tid; i < RWORDS; i += 256) dst[i] = cnt[64 + i];
  } else if (bid < KT_W1F) {
    // -------- W1 -> fragment-ordered w1f --------
    const int t = bid - KT_HISTO;          // j-block 0..7
    const int j = t * 16 + l15;
    for (int c = 0; c < 4; ++c) {
      int kbi = c * 4 + wave;              // k-block 0..15
      halfx8 h;
      for (int i = 0; i < 8; ++i) {
        int k = kbi * 32 + q4 * 8 + i;
        h[i] = (half_t)((k < KIN) ? W1[j * 488 + 2 + k] : 0.f);
      }
      *(halfx8*)&w1f[(t * 16 + kbi) * 512 + lane * 8] = h;
    }
  } else {
    // -------- W2 -> fragment-ordered w2f ; zero maxd --------
    if (tid == 0) *maxd = 0u;
    for (int i = tid; i < 128 * 128; i += 256) {
      int k8   = i & 7;
      int il15 = (i >> 3) & 15;
      int iq4  = (i >> 7) & 3;
      int ks32 = (i >> 9) & 1;
      int hh   = (i >> 10) & 1;
      int t    = i >> 11;
      int row = t * 16 + il15;
      int col = hh * 64 + ks32 * 32 + iq4 * 8 + k8;
      w2f[i] = (half_t)W2[row * 128 + col];
    }
  }
}

// ---------------------------------------------------------------- k1
// Pure U-GEMM, barrier-free K-loop (mirrors verified k_main phase B):
// A = Bt position-rows, B = w1f fragment chunks (1 KB coalesced, L2-hot).
// Same (half_t) input conversions and ascending-kb accumulation order as
// the round-4 kernel -> bit-identical U. One barrier for Ol staging.
__global__ __launch_bounds__(256) void k1(const half_t* __restrict__ Bt,
                                          const half_t* __restrict__ w1f,
                                          half_t* __restrict__ U) {
  __shared__ half_t Ol[64 * 136];          // [n][j], stride 136

  const int tid = threadIdx.x, bid = blockIdx.x;
  const int wave = tid >> 6, lane = tid & 63;
  const int l15 = lane & 15, q4 = lane >> 4;
  const int n0 = bid * 64;

  floatx4 acc[8];
  for (int t = 0; t < 8; ++t) acc[t] = (floatx4){0.f, 0.f, 0.f, 0.f};

  const half_t* bt = Bt + (long)(n0 + wave * 16 + l15) * 512 + q4 * 8;
  for (int kbi = 0; kbi < 16; ++kbi) {     // kb ascending: 0,32,...,480
    halfx8 af = *(const halfx8*)&bt[kbi * 32];
    for (int t = 0; t < 8; ++t) {
      halfx8 bf = *(const halfx8*)&w1f[(t * 16 + kbi) * 512 + lane * 8];
      acc[t] = __builtin_amdgcn_mfma_f32_16x16x32_f16(af, bf, acc[t], 0, 0, 0);
    }
  }

  // D: row = n (q4*4+r), col = j (t*16+l15)  -- same mapping as k_main C-write
  for (int t = 0; t < 8; ++t)
    for (int r = 0; r < 4; ++r)
      Ol[(wave * 16 + q4 * 4 + r) * 136 + t * 16 + l15] = (half_t)acc[t][r];
  __syncthreads();
  for (int it = 0; it < 4; ++it) {
    int idx = tid + it * 256;              // 0..1023
    int n = idx >> 4, c8 = (idx & 15) * 8;
    *(halfx8*)(U + (long)(n0 + n) * 128 + c8) = *(const halfx8*)&Ol[n * 136 + c8];
  }
}

// ---------------------------------------------------------------- k2 (tiny)
// word w packs degrees of nodes 4w..4w+3 (8-bit) in each of 32 copies; byte
// lanes can't carry (sum == true degree <= ~30). Expand to u32 deg[].
__global__ __launch_bounds__(256) void k2(const unsigned* __restrict__ degpk,
                                          unsigned* __restrict__ deg,
                                          unsigned* __restrict__ maxd) {
  const int w4 = blockIdx.x * 256 + threadIdx.x;   // uint4 index, 12500 total
  unsigned m = 0;
  if (w4 < CWORDS / 4) {
    uint4 s = make_uint4(0u, 0u, 0u, 0u);
    for (int c = 0; c < NSLICE; ++c) {
      uint4 v = *(const uint4*)&degpk[c * CWORDS + w4 * 4];
      s.x += v.x; s.y += v.y; s.z += v.z; s.w += v.w;
    }
    unsigned words[4] = {s.x, s.y, s.z, s.w};
    for (int k = 0; k < 4; ++k) {
      unsigned sw = words[k];
      uint4 o = make_uint4(sw & 255u, (sw >> 8) & 255u,
                           (sw >> 16) & 255u, sw >> 24);
      *(uint4*)&deg[w4 * 16 + k * 4] = o;
      m = max(m, max(max(o.x, o.y), max(o.z, o.w)));
    }
  }
  for (int off = 32; off > 0; off >>= 1) {
    unsigned o = (unsigned)__shfl_down((int)m, off);
    m = max(m, o);
  }
  if ((threadIdx.x & 63) == 0) atomicMax(maxd, m);
}

// ---------------------------------------------------------------- k_main
// Round-4 verbatim: phase A h1->At via LDS; phase B B-fragments direct from
// fragment-ordered w2f (L2-hot, coalesced). LDS 20.2 KB => 8 blk/CU.
__global__ __launch_bounds__(256, 8) void k_main(const float* __restrict__ vertices,
                                              const float* __restrict__ W1,
                                              const float* __restrict__ b1,
                                              const float* __restrict__ b2,
                                              const unsigned* __restrict__ deg,
                                              const unsigned* __restrict__ maxd,
                                              const half_t* __restrict__ U,
                                              const half_t* __restrict__ w2f,
                                              float* __restrict__ out) {
  __shared__ half_t At[64 * 136];    // h1 tile [node][j], stride 136
  __shared__ int   pPos[64];
  __shared__ float pW[4][64];
  __shared__ float pE[4][64];
  __shared__ float b2l[128];

  const int tid = threadIdx.x;
  const int nodeBase = blockIdx.x * 64;

  if (tid < 128) b2l[tid] = b2[tid];

  // per-node params (round-5 verbatim)
  if (tid < 64) {
    int n = nodeBase + tid;
    float vx = vertices[2 * n], vy = vertices[2 * n + 1];
    float ix = vx * (127.0f / 512.0f), iy = vy * (127.0f / 512.0f);
    float fx = floorf(ix), fy = floorf(iy);
    float wx = ix - fx, wy = iy - fy;
    int x0 = min(max((int)fx, 0), 127);
    int y0 = min(max((int)fy, 0), 127);
    pPos[tid] = y0 * 128 + x0;
    pW[0][tid] = (1.f - wx) * (1.f - wy);
    pW[1][tid] = wx * (1.f - wy);
    pW[2][tid] = (1.f - wx) * wy;
    pW[3][tid] = wx * wy;
    pE[0][tid] = vx * (1.f / 512.f);
    pE[1][tid] = vy * (1.f / 512.f);
    float md = (float)(*maxd) + 1e-6f;
    pE[2][tid] = (float)deg[n] / md;
    float dx = fminf(vx, 512.f - vx), dy = fminf(vy, 512.f - vy);
    pE[3][tid] = fminf(dx, dy) * (1.f / 256.f);
  }

  // per-thread W1 scalar-feature columns (round-5 verbatim)
  const int jp = tid & 63, q = tid >> 6;
  const int j2 = jp * 2;
  const float* r0 = W1 + j2 * 488;
  const float* r1 = r0 + 488;
  float c00 = r0[0], c01 = r0[1], c06 = r0[486], c07 = r0[487];
  float c10 = r1[0], c11 = r1[1], c16 = r1[486], c17 = r1[487];
  float bb0 = b1[j2], bb1 = b1[j2 + 1];
  __syncthreads();

  // ---- phase A (round-5 verbatim math): h1 -> At via LDS
#pragma unroll 4
  for (int it = 0; it < 16; ++it) {
    int ln = it * 4 + q;
    int pos = pPos[ln];
    float w00 = pW[0][ln], w01 = pW[1][ln], w10 = pW[2][ln], w11 = pW[3][ln];
    float cx = pE[0][ln], cy = pE[1][ln], dn = pE[2][ln], db = pE[3][ln];
    const half_t* base = U + (long)pos * 128 + j2;
    halfx2 u00 = *(const halfx2*)(base);
    halfx2 u01 = *(const halfx2*)(base + 128);
    halfx2 u10 = *(const halfx2*)(base + 16384);
    halfx2 u11 = *(const halfx2*)(base + 16512);
    float z0 = bb0 + c00 * cx + c01 * cy + c06 * dn + c07 * db
             + w00 * (float)u00.x + w01 * (float)u01.x
             + w10 * (float)u10.x + w11 * (float)u11.x;
    float z1 = bb1 + c10 * cx + c11 * cy + c16 * dn + c17 * db
             + w00 * (float)u00.y + w01 * (float)u01.y
             + w10 * (float)u10.y + w11 * (float)u11.y;
    halfx2 h;
    h.x = (half_t)fmaxf(z0, 0.f);
    h.y = (half_t)fmaxf(z1, 0.f);
    *(halfx2*)&At[ln * 136 + j2] = h;
  }
  __syncthreads();

  // ---- phase B: B-fragments direct from w2f (global, L2-hot)
  const int wave = tid >> 6, lane = tid & 63;
  const int l15 = lane & 15, q4 = lane >> 4;
  const half_t* wf = w2f + (q4 * 16 + l15) * 8;   // per-lane base in a chunk
  floatx4 acc[8];
  for (int t = 0; t < 8; ++t) acc[t] = (floatx4){0.f, 0.f, 0.f, 0.f};

  for (int h = 0; h < 2; ++h)
    for (int ks32 = 0; ks32 < 2; ++ks32) {        // k-order 0,32,64,96
      halfx8 af = *(const halfx8*)&At[(wave * 16 + l15) * 136 + h * 64 +
                                      ks32 * 32 + q4 * 8];
      for (int t = 0; t < 8; ++t) {
        halfx8 bf = *(const halfx8*)&wf[(t * 4 + h * 2 + ks32) * 512];
        acc[t] = __builtin_amdgcn_mfma_f32_16x16x32_f16(af, bf, acc[t], 0, 0, 0);
      }
    }

  for (int t = 0; t < 8; ++t) {
    int col = t * 16 + l15;
    float bias = b2l[col];
    int row0 = nodeBase + wave * 16 + q4 * 4;
    for (int r = 0; r < 4; ++r)
      out[(long)(row0 + r) * 128 + col] = fmaxf(acc[t][r] + bias, 0.f);
  }
}

// ---------------------------------------------------------------- launch
extern "C" void kernel_launch(void* const* d_in, const int* in_sizes, int n_in,
                              void* d_out, int out_size, void* d_ws, size_t ws_size,
                              hipStream_t stream) {
  const float* vertices = (const float*)d_in[0];
  const float* bb       = (const float*)d_in[1];
  const float* seg      = (const float*)d_in[2];
  const int*   edges    = (const int*)d_in[3];
  const float* W1       = (const float*)d_in[4];
  const float* b1       = (const float*)d_in[5];
  const float* W2       = (const float*)d_in[6];
  const float* b2       = (const float*)d_in[7];

  char* ws = (char*)d_ws;
  unsigned* degpk = (unsigned*)(ws + WS_DEGPK);
  unsigned* deg   = (unsigned*)(ws + WS_DEG);
  unsigned* maxd  = (unsigned*)(ws + WS_MAXD);
  half_t*   w2f   = (half_t*)(ws + WS_W2F);
  half_t*   w1f   = (half_t*)(ws + WS_W1F);
  half_t*   U     = (half_t*)(ws + WS_U);
  half_t*   Bt    = (half_t*)(ws + WS_BT);
  float*    outp  = (float*)d_out;

  kT<<<KT_GRID, 256, 0, stream>>>(bb, seg, edges, W1, W2, degpk, Bt, w1f, w2f, maxd);
  k1<<<256, 256, 0, stream>>>(Bt, w1f, U);
  k2<<<49, 256, 0, stream>>>(degpk, deg, maxd);
  k_main<<<3125, 256, 0, stream>>>(vertices, W1, b1, b2, deg, maxd, U, w2f, outp);
}